// Round 18
// baseline (164.368 us; speedup 1.0000x reference)
//
#include <hip/hip_runtime.h>

// TransitionGNN forward, v18 = v17 with 5 launches (prep merged).
// B=1024 graphs, K=10 objects, D=32, H=512. Nodes N=10240, 90 edges/graph.
//
//  megapack : ew1p[32,1024], ew2p, nw1p(576 remap), nw2p, nw3p, nbf
//  prep2    : blocks 0-63: Wfp = pack(ew3 @ nw1[36:548]) (16 rows x 256 cols)
//             blocks 64+ : PQ = X@[ew1_P|ew1_Q] (+eb1), Rb = [X|onehot]@nw1[0:64]+nbf
//  edge_v15 : per 64 edges: A=relu(P[i]+Q[j]) in-reg build, GEMM vs ew2
//             (B gl_lds dbuf), +eb2, LN, *eg+ebt, relu -> col-major restage
//             -> MFMA indicator aggregation -> Spart[b][8][512] (bf16)
//  node_hh13: Hh = relu(gather(Spart)@Wfp + R)  (gather fused into A-build)
//  node_lo  : H2 = relu(LN(Hh@nw2+nb2)*ng+nbt) (LDS only); out = H2@nw3 + nb3

#define HID 512
#define DIN 32
#define KOBJ 10
#define NGRAPH 1024
#define NNODES (NGRAPH*KOBJ)
#define NEDGE (NGRAPH*90)
#define NBLK (NEDGE/64)          // 1440
#define LN_EPS 1e-5f

typedef __bf16 bf16x8 __attribute__((ext_vector_type(8)));
typedef unsigned short u16x8 __attribute__((ext_vector_type(8)));
typedef unsigned short u16x4 __attribute__((ext_vector_type(4)));
typedef float f32x4 __attribute__((ext_vector_type(4)));

__device__ __forceinline__ unsigned short f2bf(float f) {
    unsigned u = __builtin_bit_cast(unsigned, f);
    u += 0x7fffu + ((u >> 16) & 1u);          // RNE
    return (unsigned short)(u >> 16);
}
__device__ __forceinline__ float bf2f(unsigned short h) {
    unsigned u = ((unsigned)h) << 16;
    return __builtin_bit_cast(float, u);
}
__device__ __forceinline__ void gl_lds16(const void* g, void* l) {
    __builtin_amdgcn_global_load_lds(
        (__attribute__((address_space(1))) void*)g,
        (__attribute__((address_space(3))) void*)l, 16, 0, 0);
}

// ---------------------------------------------------------------------------
// megapack: ew1p | ew2p | nw1p | nw2p | nw3p | nbf in one launch.
__global__ void megapack(const float* __restrict__ ew1, const float* __restrict__ ew2,
                         const float* __restrict__ nw1, const float* __restrict__ nw2,
                         const float* __restrict__ nw3, const float* __restrict__ nb1,
                         const float* __restrict__ eb3,
                         unsigned short* __restrict__ ew1p, unsigned short* __restrict__ ew2p,
                         unsigned short* __restrict__ nw1p, unsigned short* __restrict__ nw2p,
                         unsigned short* __restrict__ nw3p, float* __restrict__ nbf)
{
    int idx = blockIdx.x * 256 + threadIdx.x;
    if (idx < 32768) {                                   // ew1p [32,1024]
        int j = idx & 7, c = (idx >> 3) & 1023, kb = idx >> 13;
        int k = kb * 8 + j;
        float v = (c < 512) ? ew1[(size_t)k * 512 + c]
                            : ew1[(size_t)(32 + k) * 512 + (c - 512)];
        ew1p[idx] = f2bf(v);
    } else if (idx < 32768 + 262144) {                   // ew2p
        int i = idx - 32768;
        int j = i & 7, c = (i >> 3) & 511, kb = i >> 12;
        ew2p[i] = f2bf(ew2[(size_t)(kb * 8 + j) * 512 + c]);
    } else if (idx < 294912 + 294912) {                  // nw1p (576 rows, remap)
        int i = idx - 294912;
        int j = i & 7, c = (i >> 3) & 511, kb = i >> 12;
        int k = kb * 8 + j;
        int sk = (k < 36) ? k : (k < 64 ? -1 : k - 28);
        nw1p[i] = f2bf(sk < 0 ? 0.f : nw1[(size_t)sk * 512 + c]);
    } else if (idx < 589824 + 262144) {                  // nw2p
        int i = idx - 589824;
        int j = i & 7, c = (i >> 3) & 511, kb = i >> 12;
        nw2p[i] = f2bf(nw2[(size_t)(kb * 8 + j) * 512 + c]);
    } else if (idx < 851968 + 16384) {                   // nw3p [512,32]
        int i = idx - 851968;
        int j = i & 7, c2 = (i >> 3) & 31, kb = i >> 8;
        nw3p[i] = f2bf(nw3[(size_t)(kb * 8 + j) * 32 + c2]);
    } else if (idx < 868352 + 512) {                     // nbf
        int c = idx - 868352;
        float s = 0.f;
        for (int m = 0; m < 512; ++m)
            s = fmaf(eb3[m], nw1[(size_t)(36 + m) * 512 + c], s);
        nbf[c] = nb1[c] + 9.f * s;
    }
}

// ---------------------------------------------------------------------------
// prep2: blocks 0..63 -> fold (Wfp half-tiles); blocks 64.. -> pq_xa. 256 thr.
__global__ __launch_bounds__(256) void prep2(
    const float* __restrict__ ew3, const float* __restrict__ X,
    const int* __restrict__ act,
    const unsigned short* __restrict__ ew1p, const unsigned short* __restrict__ nw1p,
    const float* __restrict__ eb1, const float* __restrict__ nbf,
    unsigned short* __restrict__ Wfp, unsigned short* __restrict__ PQ,
    unsigned short* __restrict__ Rb)
{
    const int t = threadIdx.x, w = t >> 6, lane = t & 63;
    const int lr = lane & 15, lg = lane >> 4;
    const int bx = blockIdx.x;

    if (bx < 64) {
        // fold: Wfp = pack(ew3 @ nw1[36:548]); 16 rows x 256 cols per block
        const int rb = (bx >> 1) * 16;
        const int ch = bx & 1;                     // column half
        f32x4 acc[4] = {};
        for (int kc = 0; kc < 16; ++kc) {
            const float* s = ew3 + (size_t)(rb + lr) * 512 + kc * 32 + lg * 8;
            float4 x0 = *(const float4*)s, x1 = *(const float4*)(s + 4);
            u16x8 u;
            u[0] = f2bf(x0.x); u[1] = f2bf(x0.y); u[2] = f2bf(x0.z); u[3] = f2bf(x0.w);
            u[4] = f2bf(x1.x); u[5] = f2bf(x1.y); u[6] = f2bf(x1.z); u[7] = f2bf(x1.w);
            bf16x8 a = __builtin_bit_cast(bf16x8, u);
            const size_t kb = (size_t)(8 + kc * 4 + lg) * 512;
#pragma unroll
            for (int nt = 0; nt < 4; ++nt) {
                int c = ch * 256 + w * 64 + nt * 16 + lr;
                bf16x8 b = __builtin_bit_cast(bf16x8, *(const u16x8*)(nw1p + (kb + c) * 8));
                acc[nt] = __builtin_amdgcn_mfma_f32_16x16x32_bf16(a, b, acc[nt], 0, 0, 0);
            }
        }
#pragma unroll
        for (int reg = 0; reg < 4; ++reg)
#pragma unroll
            for (int nt = 0; nt < 4; ++nt) {
                int k = rb + lg * 4 + reg;
                int c = ch * 256 + w * 64 + nt * 16 + lr;
                Wfp[((size_t)(k >> 3) * 512 + c) * 8 + (k & 7)] = f2bf(acc[nt][reg]);
            }
        return;
    }

    // pq_xa part
    const int pq = bx - 64;
    const int rb = (pq % 320) * 32;
    const int mode = pq / 320;

    bf16x8 a[2];
#pragma unroll
    for (int m = 0; m < 2; ++m) {
        const float* s = X + (size_t)(rb + m * 16 + lr) * 32 + lg * 8;
        float4 x0 = *(const float4*)s, x1 = *(const float4*)(s + 4);
        u16x8 u;
        u[0] = f2bf(x0.x); u[1] = f2bf(x0.y); u[2] = f2bf(x0.z); u[3] = f2bf(x0.w);
        u[4] = f2bf(x1.x); u[5] = f2bf(x1.y); u[6] = f2bf(x1.z); u[7] = f2bf(x1.w);
        a[m] = __builtin_bit_cast(bf16x8, u);
    }

    if (mode < 2) {
        const int half = mode;
        f32x4 acc[2][8] = {};
#pragma unroll
        for (int nt = 0; nt < 8; ++nt) {
            int col = half * 512 + w * 128 + nt * 16 + lr;
            bf16x8 b = __builtin_bit_cast(bf16x8, *(const u16x8*)(ew1p + ((size_t)lg * 1024 + col) * 8));
            acc[0][nt] = __builtin_amdgcn_mfma_f32_16x16x32_bf16(a[0], b, acc[0][nt], 0, 0, 0);
            acc[1][nt] = __builtin_amdgcn_mfma_f32_16x16x32_bf16(a[1], b, acc[1][nt], 0, 0, 0);
        }
#pragma unroll
        for (int nt = 0; nt < 8; ++nt) {
            int col = w * 128 + nt * 16 + lr;
            float eb = (half == 0) ? eb1[col] : 0.f;
#pragma unroll
            for (int m = 0; m < 2; ++m)
#pragma unroll
                for (int reg = 0; reg < 4; ++reg)
                    PQ[(size_t)(rb + m * 16 + lg * 4 + reg) * 1024 + half * 512 + col]
                        = f2bf(acc[m][nt][reg] + eb);
        }
    } else {
        bf16x8 a1[2];
#pragma unroll
        for (int m = 0; m < 2; ++m) {
            int row = rb + m * 16 + lr;
            u16x8 v = (u16x8)(unsigned short)0;
            if (lg == 0) {
                int ac = act[row / KOBJ];
                v[ac & 3] = (unsigned short)0x3f80;    // bf16(1.0) at k=32+ac
            }
            a1[m] = __builtin_bit_cast(bf16x8, v);
        }
        f32x4 acc[2][8] = {};
#pragma unroll
        for (int nt = 0; nt < 8; ++nt) {
            int col = w * 128 + nt * 16 + lr;
            bf16x8 b0 = __builtin_bit_cast(bf16x8, *(const u16x8*)(nw1p + ((size_t)lg * 512 + col) * 8));
            bf16x8 b1 = __builtin_bit_cast(bf16x8, *(const u16x8*)(nw1p + ((size_t)(4 + lg) * 512 + col) * 8));
#pragma unroll
            for (int m = 0; m < 2; ++m) {
                acc[m][nt] = __builtin_amdgcn_mfma_f32_16x16x32_bf16(a[m], b0, acc[m][nt], 0, 0, 0);
                acc[m][nt] = __builtin_amdgcn_mfma_f32_16x16x32_bf16(a1[m], b1, acc[m][nt], 0, 0, 0);
            }
        }
#pragma unroll
        for (int nt = 0; nt < 8; ++nt) {
            int col = w * 128 + nt * 16 + lr;
            float bb = nbf[col];
#pragma unroll
            for (int m = 0; m < 2; ++m)
#pragma unroll
                for (int reg = 0; reg < 4; ++reg)
                    Rb[(size_t)(rb + m * 16 + lg * 4 + reg) * 512 + col]
                        = f2bf(acc[m][nt][reg] + bb);
        }
    }
}

// ---------------------------------------------------------------------------
// edge_v15 (unchanged, proven 96.3 us).
__global__ __launch_bounds__(512, 4) void edge_v15(
    const unsigned short* __restrict__ PQ, const unsigned short* __restrict__ ew2p,
    const float* __restrict__ eb2, const float* __restrict__ eg,
    const float* __restrict__ ebt, unsigned short* __restrict__ Spart)
{
    __shared__ __align__(16) char ldsraw[77824];   // B dbuf | A dbuf; epilogue: Hcol
    __shared__ float sums[64], ssums[64];
    unsigned short* Hcol = (unsigned short*)ldsraw;          // stride 72 u16/col

    const int t = threadIdx.x, w = t >> 6, lane = t & 63;
    const int lr = lane & 15, lg = lane >> 4;
    const int wr = w >> 2, wc = w & 3;
    const int rb = blockIdx.x * 64;

    if (t < 64) { sums[t] = 0.f; ssums[t] = 0.f; }

    const bool ab = (t < 256);
    const int arow = t >> 2, akg = t & 3;
    const int e = rb + arow;
    const int g = e / 90, le = e - g * 90;
    const int i = le / 9, jj = le - i * 9;
    const int j = jj + (jj >= i);
    const unsigned short* pqP = PQ + ((size_t)(g * KOBJ + i)) * 1024 + akg * 8;
    const unsigned short* pqQ = PQ + ((size_t)(g * KOBJ + j)) * 1024 + 512 + akg * 8;

    u16x8 rp = (u16x8)(unsigned short)0, rq = (u16x8)(unsigned short)0;
    auto loadPQ = [&](int kc) {
        if (ab) {
            rp = *(const u16x8*)(pqP + kc * 32);
            rq = *(const u16x8*)(pqQ + kc * 32);
        }
    };
    auto buildA = [&](int buf) {
        if (ab) {
            u16x8 o;
#pragma unroll
            for (int q = 0; q < 8; ++q)
                o[q] = f2bf(fmaxf(bf2f(rp[q]) + bf2f(rq[q]), 0.f));
            *(u16x8*)(ldsraw + 65536 + buf * 5120 + arow * 80 + akg * 16) = o;
        }
    };
    auto fillB = [&](int kc, int buf) {
        char* Bb = ldsraw + buf * 32768;
#pragma unroll
        for (int RR = 0; RR < 4; ++RR)
            gl_lds16(ew2p + (size_t)kc * 16384 + RR * 4096 + t * 8, Bb + RR * 8192 + w * 1024);
    };

    f32x4 acc[2][8] = {};
    loadPQ(0); buildA(0); loadPQ(1); fillB(0, 0);
    __syncthreads();
    int cur = 0;
    for (int kc = 0; kc < 16; ++kc) {
        if (kc < 15) {
            fillB(kc + 1, cur ^ 1);
            buildA(cur ^ 1);                   // consumes regs prefetched for kc+1
            if (kc < 14) loadPQ(kc + 2);
        }
        const unsigned short* Ab = (const unsigned short*)(ldsraw + 65536 + cur * 5120);
        const unsigned short* Bb = (const unsigned short*)(ldsraw + cur * 32768);
        bf16x8 a0 = *(const bf16x8*)(Ab + (wr * 32 + lr) * 40 + lg * 8);
        bf16x8 a1 = *(const bf16x8*)(Ab + (wr * 32 + 16 + lr) * 40 + lg * 8);
#pragma unroll
        for (int nt = 0; nt < 8; ++nt) {
            bf16x8 b = *(const bf16x8*)(Bb + ((size_t)lg * 512 + wc * 128 + nt * 16 + lr) * 8);
            acc[0][nt] = __builtin_amdgcn_mfma_f32_16x16x32_bf16(a0, b, acc[0][nt], 0, 0, 0);
            acc[1][nt] = __builtin_amdgcn_mfma_f32_16x16x32_bf16(a1, b, acc[1][nt], 0, 0, 0);
        }
        __syncthreads();
        cur ^= 1;
    }

    float b2[8], gv[8], bb[8];
#pragma unroll
    for (int nt = 0; nt < 8; ++nt) {
        int c = wc * 128 + nt * 16 + lr;
        b2[nt] = eb2[c]; gv[nt] = eg[c]; bb[nt] = ebt[c];
    }
#pragma unroll
    for (int m = 0; m < 2; ++m)
#pragma unroll
        for (int reg = 0; reg < 4; ++reg) {
            float s = 0.f, ss = 0.f;
#pragma unroll
            for (int nt = 0; nt < 8; ++nt) {
                float v = acc[m][nt][reg] + b2[nt];
                acc[m][nt][reg] = v;
                s += v; ss += v * v;
            }
#pragma unroll
            for (int msk = 1; msk < 16; msk <<= 1) {
                s  += __shfl_xor(s,  msk, 64);
                ss += __shfl_xor(ss, msk, 64);
            }
            if (lr == 0) {
                int rl = wr * 32 + m * 16 + lg * 4 + reg;
                atomicAdd(&sums[rl], s);
                atomicAdd(&ssums[rl], ss);
            }
        }
    __syncthreads();

#pragma unroll
    for (int m = 0; m < 2; ++m)
#pragma unroll
        for (int nt = 0; nt < 8; ++nt) {
            int c = wc * 128 + nt * 16 + lr;
            u16x4 o;
#pragma unroll
            for (int reg = 0; reg < 4; ++reg) {
                int rl = wr * 32 + m * 16 + lg * 4 + reg;
                float mean = sums[rl] * (1.f / 512.f);
                float var  = ssums[rl] * (1.f / 512.f) - mean * mean;
                float inv  = rsqrtf(var + LN_EPS);
                float h = fmaxf((acc[m][nt][reg] - mean) * inv * gv[nt] + bb[nt], 0.f);
                o[reg] = f2bf(h);
            }
            *(u16x4*)(&Hcol[c * 72 + wr * 32 + m * 16 + lg * 4]) = o;
        }
    __syncthreads();

    // MFMA aggregation: Spart[node][col] = I[node][row] @ H[row][col]  (bf16 out)
    {
        const int n0 = rb / 9;
        f32x4 sacc[4] = {};
#pragma unroll
        for (int kc2 = 0; kc2 < 2; ++kc2) {
            u16x8 ia;
#pragma unroll
            for (int q = 0; q < 8; ++q) {
                int k = kc2 * 32 + lg * 8 + q;
                int node = (rb + k) / 9 - n0;            // 0..7
                ia[q] = (node == lr) ? (unsigned short)0x3F80 : (unsigned short)0;
            }
            bf16x8 af = __builtin_bit_cast(bf16x8, ia);
#pragma unroll
            for (int nt = 0; nt < 4; ++nt) {
                int c = w * 64 + nt * 16 + lr;
                bf16x8 bf = *(const bf16x8*)(&Hcol[c * 72 + kc2 * 32 + lg * 8]);
                sacc[nt] = __builtin_amdgcn_mfma_f32_16x16x32_bf16(af, bf, sacc[nt], 0, 0, 0);
            }
        }
        if (lg < 2) {
            unsigned short* dst = Spart + (size_t)blockIdx.x * 4096;
#pragma unroll
            for (int nt = 0; nt < 4; ++nt)
#pragma unroll
                for (int reg = 0; reg < 4; ++reg) {
                    int node = lg * 4 + reg;
                    int c = w * 64 + nt * 16 + lr;
                    dst[node * 512 + c] = f2bf(sacc[nt][reg]);
                }
        }
    }
}

// ---------------------------------------------------------------------------
// node_hh13: Hh = relu(gather(Spart)@Wfp + R). Grid (160,2). (proven v17)
__global__ __launch_bounds__(512, 4) void node_hh13(
    const unsigned short* __restrict__ Spart, const unsigned short* __restrict__ Wfp,
    const unsigned short* __restrict__ Rb, unsigned short* __restrict__ Hh)
{
    __shared__ __align__(16) unsigned short Bsh[2][8192];   // 2 x 16KB [kbl][256][8]
    __shared__ __align__(16) unsigned short Ash[2][2560];   // 2 x 5KB  [row*40 + k]
    const int t = threadIdx.x, w = t >> 6, lane = t & 63;
    const int lr = lane & 15, lg = lane >> 4;
    const int wr = w >> 2, wc = w & 3;
    const int rb = blockIdx.x * 64;
    const int nh = blockIdx.y;                              // col base nh*256

    const bool ab = (t < 256);
    const int arow = t >> 2, akg = t & 3;
    const int n = rb + arow;
    const int e0 = 9 * n;
    const int b1 = e0 >> 6, b2 = (e0 + 8) >> 6;
    const int nl1 = n - (b1 * 64) / 9;
    const int nl2 = n - (b2 * 64) / 9;
    const unsigned short* p1 = Spart + ((size_t)b1 * 8 + nl1) * 512 + akg * 8;
    const unsigned short* p2 = Spart + ((size_t)b2 * 8 + nl2) * 512 + akg * 8;
    const bool two = (b2 != b1);

    u16x8 r1 = (u16x8)(unsigned short)0, r2 = (u16x8)(unsigned short)0;
    auto loadA = [&](int kc) {
        if (ab) {
            r1 = *(const u16x8*)(p1 + kc * 32);
            if (two) r2 = *(const u16x8*)(p2 + kc * 32);
        }
    };
    auto buildA = [&](int buf) {
        if (ab) {
            u16x8 o;
#pragma unroll
            for (int q = 0; q < 8; ++q) {
                float s = bf2f(r1[q]) + (two ? bf2f(r2[q]) : 0.f);
                o[q] = f2bf(s);
            }
            *(u16x8*)(&Ash[buf][arow * 40 + akg * 8]) = o;
        }
    };
    auto fillB = [&](int kc, int buf) {
        char* Bb = (char*)&Bsh[buf][0];
#pragma unroll
        for (int RR = 0; RR < 2; ++RR) {
            int gi = RR * 512 + t;
            int kbl = gi >> 8, col = gi & 255;
            gl_lds16(Wfp + ((size_t)(kc * 4 + kbl) * 512 + nh * 256 + col) * 8,
                     Bb + RR * 8192 + w * 1024);
        }
    };

    f32x4 acc[2][4] = {};
    loadA(0); buildA(0); loadA(1); fillB(0, 0);
    __syncthreads();
    int cur = 0;
    for (int kc = 0; kc < 16; ++kc) {
        if (kc < 15) {
            fillB(kc + 1, cur ^ 1);
            buildA(cur ^ 1);
            if (kc < 14) loadA(kc + 2);
        }
        const unsigned short* Ab = &Ash[cur][0];
        const unsigned short* Bb = &Bsh[cur][0];
        bf16x8 a0 = *(const bf16x8*)(Ab + (wr * 32 + lr) * 40 + lg * 8);
        bf16x8 a1 = *(const bf16x8*)(Ab + (wr * 32 + 16 + lr) * 40 + lg * 8);
#pragma unroll
        for (int nt = 0; nt < 4; ++nt) {
            bf16x8 b = *(const bf16x8*)(Bb + ((size_t)lg * 256 + wc * 64 + nt * 16 + lr) * 8);
            acc[0][nt] = __builtin_amdgcn_mfma_f32_16x16x32_bf16(a0, b, acc[0][nt], 0, 0, 0);
            acc[1][nt] = __builtin_amdgcn_mfma_f32_16x16x32_bf16(a1, b, acc[1][nt], 0, 0, 0);
        }
        __syncthreads();
        cur ^= 1;
    }

#pragma unroll
    for (int m = 0; m < 2; ++m)
#pragma unroll
        for (int reg = 0; reg < 4; ++reg) {
            int row = rb + wr * 32 + m * 16 + lg * 4 + reg;
#pragma unroll
            for (int nt = 0; nt < 4; ++nt) {
                int c = nh * 256 + wc * 64 + nt * 16 + lr;
                float v = acc[m][nt][reg] + bf2f(Rb[(size_t)row * 512 + c]);
                Hh[(size_t)row * 512 + c] = f2bf(fmaxf(v, 0.f));
            }
        }
}

// ---------------------------------------------------------------------------
// node_lo: H2 = relu(LN(Hh@nw2 + nb2)*ng+nbt) kept in LDS; out = H2@nw3 + nb3.
__global__ __launch_bounds__(512, 4) void node_lo(
    const unsigned short* __restrict__ A, const unsigned short* __restrict__ Wp,
    const float* __restrict__ bias, const float* __restrict__ gamma,
    const float* __restrict__ beta, const unsigned short* __restrict__ nw3p,
    const float* __restrict__ nb3, float* __restrict__ out)
{
    __shared__ __align__(16) char raw[69632];      // 64KB Bt | 4KB At
    __shared__ float sums[32], ssums[32];
    unsigned short* Bt = (unsigned short*)raw;
    unsigned short* At = (unsigned short*)(raw + 65536);
    const int t = threadIdx.x, w = t >> 6, lane = t & 63;
    const int lr = lane & 15, lg = lane >> 4;
    const int rb = blockIdx.x * 32;
    if (t < 32) { sums[t] = 0.f; ssums[t] = 0.f; }

    f32x4 acc[2][4] = {};
    for (int kc = 0; kc < 8; ++kc) {
        __syncthreads();
#pragma unroll
        for (int RR = 0; RR < 8; ++RR)
            gl_lds16(Wp + ((size_t)kc * 4096 + RR * 512 + t) * 8,
                     raw + RR * 8192 + w * 1024);
        if (w < 4) {
            int row = t >> 3, cp = t & 7;
            int scol = cp ^ (row & 7);
            gl_lds16(A + (size_t)(rb + row) * 512 + kc * 64 + scol * 8,
                     raw + 65536 + (t & ~63) * 16);
        }
        __syncthreads();
#pragma unroll
        for (int ks = 0; ks < 2; ++ks) {
            int kidx = ks * 4 + lg;
            bf16x8 a0 = *(const bf16x8*)(At + ( 0 + lr) * 64 + (kidx ^ (lr & 7)) * 8);
            bf16x8 a1 = *(const bf16x8*)(At + (16 + lr) * 64 + (kidx ^ (lr & 7)) * 8);
#pragma unroll
            for (int nt = 0; nt < 4; ++nt) {
                bf16x8 b = *(const bf16x8*)(Bt + ((size_t)kidx * 512 + w * 64 + nt * 16 + lr) * 8);
                acc[0][nt] = __builtin_amdgcn_mfma_f32_16x16x32_bf16(a0, b, acc[0][nt], 0, 0, 0);
                acc[1][nt] = __builtin_amdgcn_mfma_f32_16x16x32_bf16(a1, b, acc[1][nt], 0, 0, 0);
            }
        }
    }

    float bv[4], gv[4], be[4];
#pragma unroll
    for (int nt = 0; nt < 4; ++nt) {
        int c = w * 64 + nt * 16 + lr;
        bv[nt] = bias[c]; gv[nt] = gamma[c]; be[nt] = beta[c];
    }
#pragma unroll
    for (int m = 0; m < 2; ++m)
#pragma unroll
        for (int reg = 0; reg < 4; ++reg) {
            float s = 0.f, ss = 0.f;
#pragma unroll
            for (int nt = 0; nt < 4; ++nt) {
                float v = acc[m][nt][reg] + bv[nt];
                acc[m][nt][reg] = v;
                s += v; ss += v * v;
            }
#pragma unroll
            for (int msk = 1; msk < 16; msk <<= 1) {
                s  += __shfl_xor(s,  msk, 64);
                ss += __shfl_xor(ss, msk, 64);
            }
            if (lr == 0) {
                atomicAdd(&sums [m * 16 + lg * 4 + reg], s);
                atomicAdd(&ssums[m * 16 + lg * 4 + reg], ss);
            }
        }
    __syncthreads();   // stats done; loop LDS reads done -> raw reusable

    // normalize + relu -> Hst[32][520] u16 (LDS only)
    unsigned short* Hst = (unsigned short*)raw;
#pragma unroll
    for (int m = 0; m < 2; ++m)
#pragma unroll
        for (int reg = 0; reg < 4; ++reg) {
            int rl = m * 16 + lg * 4 + reg;
            float mean = sums[rl] * (1.f / 512.f);
            float var  = ssums[rl] * (1.f / 512.f) - mean * mean;
            float inv  = rsqrtf(var + LN_EPS);
#pragma unroll
            for (int nt = 0; nt < 4; ++nt) {
                int c = w * 64 + nt * 16 + lr;
                float v = fmaxf((acc[m][nt][reg] - mean) * inv * gv[nt] + be[nt], 0.f);
                Hst[rl * 520 + c] = f2bf(v);
            }
        }
    __syncthreads();

    // out-GEMM: wave w handles k in [w*64, w*64+64).
    float* Pp = (float*)(raw + 34816);           // [8][32][32] f32
    {
        f32x4 acc2[2][2] = {};
#pragma unroll
        for (int kc3 = 0; kc3 < 2; ++kc3) {
            int kbase = w * 64 + kc3 * 32;
            bf16x8 a0 = *(const bf16x8*)(Hst + ( 0 + lr) * 520 + kbase + lg * 8);
            bf16x8 a1 = *(const bf16x8*)(Hst + (16 + lr) * 520 + kbase + lg * 8);
#pragma unroll
            for (int ntt = 0; ntt < 2; ++ntt) {
                int kb = (kbase >> 3) + lg;
                bf16x8 b = __builtin_bit_cast(bf16x8,
                    *(const u16x8*)(nw3p + ((size_t)kb * 32 + ntt * 16 + lr) * 8));
                acc2[0][ntt] = __builtin_amdgcn_mfma_f32_16x16x32_bf16(a0, b, acc2[0][ntt], 0, 0, 0);
                acc2[1][ntt] = __builtin_amdgcn_mfma_f32_16x16x32_bf16(a1, b, acc2[1][ntt], 0, 0, 0);
            }
        }
        __syncthreads();
#pragma unroll
        for (int mt = 0; mt < 2; ++mt)
#pragma unroll
            for (int ntt = 0; ntt < 2; ++ntt)
#pragma unroll
                for (int reg = 0; reg < 4; ++reg) {
                    int row = mt * 16 + lg * 4 + reg;
                    int col = ntt * 16 + lr;
                    Pp[(size_t)w * 1024 + row * 32 + col] = acc2[mt][ntt][reg];
                }
    }
    __syncthreads();

    for (int e2 = t; e2 < 1024; e2 += 512) {
        int row = e2 >> 5, col = e2 & 31;
        float s = 0.f;
#pragma unroll
        for (int ww = 0; ww < 8; ++ww) s += Pp[(size_t)ww * 1024 + e2];
        out[(size_t)(rb + row) * 32 + col] = s + nb3[col];
    }
}

// ---------------------------------------------------------------------------
extern "C" void kernel_launch(void* const* d_in, const int* in_sizes, int n_in,
                              void* d_out, int out_size, void* d_ws, size_t ws_size,
                              hipStream_t stream)
{
    const float* states = (const float*)d_in[0];
    const int*   action = (const int*)d_in[1];
    const float* ew1 = (const float*)d_in[2];
    const float* eb1 = (const float*)d_in[3];
    const float* ew2 = (const float*)d_in[4];
    const float* eb2 = (const float*)d_in[5];
    const float* eg  = (const float*)d_in[6];
    const float* ebt = (const float*)d_in[7];
    const float* ew3 = (const float*)d_in[8];
    const float* eb3 = (const float*)d_in[9];
    const float* nw1 = (const float*)d_in[10];
    const float* nb1 = (const float*)d_in[11];
    const float* nw2 = (const float*)d_in[12];
    const float* nb2 = (const float*)d_in[13];
    const float* ng  = (const float*)d_in[14];
    const float* nbt = (const float*)d_in[15];
    const float* nw3 = (const float*)d_in[16];
    const float* nb3 = (const float*)d_in[17];

    char* wsb = (char*)d_ws;
    unsigned short* PQ    = (unsigned short*)(wsb);               // 10240x1024 bf16
    unsigned short* Spart = (unsigned short*)(wsb + 20971520);    // 1440x8x512 bf16
    unsigned short* Rb    = (unsigned short*)(wsb + 43253760);    // 10240x512 bf16
    unsigned short* Hh    = (unsigned short*)(wsb + 53739520);    // 10240x512 bf16
    unsigned short* ew1p  = (unsigned short*)(wsb + 74711040);    // 32x1024
    unsigned short* ew2p  = (unsigned short*)(wsb + 74776576);    // 512x512 packed
    unsigned short* nw1p  = (unsigned short*)(wsb + 75300864);    // 576x512 packed
    unsigned short* nw2p  = (unsigned short*)(wsb + 75890688);    // 512x512 packed
    unsigned short* Wfp   = (unsigned short*)(wsb + 76414976);    // 512x512 packed
    float*          nbf   = (float*)         (wsb + 76939264);    // 512 f32
    unsigned short* nw3p  = (unsigned short*)(wsb + 76941312);    // 512x32 packed
    float* out = (float*)d_out;

    hipLaunchKernelGGL(megapack, dim3(3394), dim3(256), 0, stream,
                       ew1, ew2, nw1, nw2, nw3, nb1, eb3,
                       ew1p, ew2p, nw1p, nw2p, nw3p, nbf);
    hipLaunchKernelGGL(prep2, dim3(1024), dim3(256), 0, stream,
                       ew3, states, action, ew1p, nw1p, eb1, nbf, Wfp, PQ, Rb);
    hipLaunchKernelGGL(edge_v15, dim3(NBLK), dim3(512), 0, stream,
                       PQ, ew2p, eb2, eg, ebt, Spart);
    hipLaunchKernelGGL(node_hh13, dim3(160, 2), dim3(512), 0, stream,
                       Spart, Wfp, Rb, Hh);
    hipLaunchKernelGGL(node_lo, dim3(320), dim3(512), 0, stream,
                       Hh, nw2p, nb2, ng, nbt, nw3p, nb3, out);
}

// Round 19
// 162.388 us; speedup vs baseline: 1.0122x; 1.0122x over previous
//
#include <hip/hip_runtime.h>

// TransitionGNN forward, v19 = R17 best config verbatim (162.8 us).
// B=1024 graphs, K=10 objects, D=32, H=512. Nodes N=10240, 90 edges/graph.
//
//  megapack : ew1p[32,1024], ew2p, nw1p(576 remap), nw2p, nw3p
//  fold_w2  : Wfp = pack(ew3 @ nw1[36:548]) ; nbf = nb1 + 9*eb3@nw1[36:548]
//  pq_xa    : PQ[10240][1024] = X@[ew1_P|ew1_Q] (+eb1 on P half)
//             R[10240][512] bf16 = [X|onehot]@nw1[0:64] + nbf
//  edge_v15 : per 64 edges: A=relu(P[i]+Q[j]) in-reg build, GEMM vs ew2
//             (B gl_lds dbuf), +eb2, LN, *eg+ebt, relu -> col-major restage
//             -> MFMA indicator aggregation -> Spart[b][8][512] (bf16)
//  node_hh13: Hh = relu(gather(Spart)@Wfp + R)  (gather fused into A-build)
//  node_lo  : H2 = relu(LN(Hh@nw2+nb2)*ng+nbt) (LDS only); out = H2@nw3 + nb3

#define HID 512
#define DIN 32
#define KOBJ 10
#define NGRAPH 1024
#define NNODES (NGRAPH*KOBJ)
#define NEDGE (NGRAPH*90)
#define NBLK (NEDGE/64)          // 1440
#define LN_EPS 1e-5f

typedef __bf16 bf16x8 __attribute__((ext_vector_type(8)));
typedef unsigned short u16x8 __attribute__((ext_vector_type(8)));
typedef unsigned short u16x4 __attribute__((ext_vector_type(4)));
typedef float f32x4 __attribute__((ext_vector_type(4)));

__device__ __forceinline__ unsigned short f2bf(float f) {
    unsigned u = __builtin_bit_cast(unsigned, f);
    u += 0x7fffu + ((u >> 16) & 1u);          // RNE
    return (unsigned short)(u >> 16);
}
__device__ __forceinline__ float bf2f(unsigned short h) {
    unsigned u = ((unsigned)h) << 16;
    return __builtin_bit_cast(float, u);
}
__device__ __forceinline__ void gl_lds16(const void* g, void* l) {
    __builtin_amdgcn_global_load_lds(
        (__attribute__((address_space(1))) void*)g,
        (__attribute__((address_space(3))) void*)l, 16, 0, 0);
}

// ---------------------------------------------------------------------------
// megapack: ew1p | ew2p | nw1p | nw2p | nw3p in one launch.
__global__ void megapack(const float* __restrict__ ew1, const float* __restrict__ ew2,
                         const float* __restrict__ nw1, const float* __restrict__ nw2,
                         const float* __restrict__ nw3,
                         unsigned short* __restrict__ ew1p, unsigned short* __restrict__ ew2p,
                         unsigned short* __restrict__ nw1p, unsigned short* __restrict__ nw2p,
                         unsigned short* __restrict__ nw3p)
{
    int idx = blockIdx.x * 256 + threadIdx.x;
    if (idx < 32768) {                                   // ew1p [32,1024]
        int j = idx & 7, c = (idx >> 3) & 1023, kb = idx >> 13;
        int k = kb * 8 + j;
        float v = (c < 512) ? ew1[(size_t)k * 512 + c]
                            : ew1[(size_t)(32 + k) * 512 + (c - 512)];
        ew1p[idx] = f2bf(v);
    } else if (idx < 32768 + 262144) {                   // ew2p
        int i = idx - 32768;
        int j = i & 7, c = (i >> 3) & 511, kb = i >> 12;
        ew2p[i] = f2bf(ew2[(size_t)(kb * 8 + j) * 512 + c]);
    } else if (idx < 294912 + 294912) {                  // nw1p (576 rows, remap)
        int i = idx - 294912;
        int j = i & 7, c = (i >> 3) & 511, kb = i >> 12;
        int k = kb * 8 + j;
        int sk = (k < 36) ? k : (k < 64 ? -1 : k - 28);
        nw1p[i] = f2bf(sk < 0 ? 0.f : nw1[(size_t)sk * 512 + c]);
    } else if (idx < 589824 + 262144) {                  // nw2p
        int i = idx - 589824;
        int j = i & 7, c = (i >> 3) & 511, kb = i >> 12;
        nw2p[i] = f2bf(nw2[(size_t)(kb * 8 + j) * 512 + c]);
    } else if (idx < 851968 + 16384) {                   // nw3p [512,32]
        int i = idx - 851968;
        int j = i & 7, c2 = (i >> 3) & 31, kb = i >> 8;
        nw3p[i] = f2bf(nw3[(size_t)(kb * 8 + j) * 32 + c2]);
    }
}

// ---------------------------------------------------------------------------
// fold_w2: blocks 0..31: Wfp = pack(ew3 @ nw1[36:548]); block 32: nbf fold.
__global__ __launch_bounds__(512) void fold_w2(
    const float* __restrict__ ew3, const unsigned short* __restrict__ nw1p,
    const float* __restrict__ nw1, const float* __restrict__ nb1,
    const float* __restrict__ eb3, unsigned short* __restrict__ Wfp,
    float* __restrict__ nbf)
{
    if (blockIdx.x == 32) {
        int c = threadIdx.x;
        if (c < 512) {
            float s = 0.f;
            for (int m = 0; m < 512; ++m)
                s = fmaf(eb3[m], nw1[(size_t)(36 + m) * 512 + c], s);
            nbf[c] = nb1[c] + 9.f * s;
        }
        return;
    }
    const int t = threadIdx.x, w = t >> 6, lane = t & 63;
    const int lr = lane & 15, lg = lane >> 4;
    const int rb = blockIdx.x * 16;
    f32x4 acc[4] = {};
    for (int kc = 0; kc < 16; ++kc) {
        const float* s = ew3 + (size_t)(rb + lr) * 512 + kc * 32 + lg * 8;
        float4 x0 = *(const float4*)s, x1 = *(const float4*)(s + 4);
        u16x8 u;
        u[0] = f2bf(x0.x); u[1] = f2bf(x0.y); u[2] = f2bf(x0.z); u[3] = f2bf(x0.w);
        u[4] = f2bf(x1.x); u[5] = f2bf(x1.y); u[6] = f2bf(x1.z); u[7] = f2bf(x1.w);
        bf16x8 a = __builtin_bit_cast(bf16x8, u);
        const size_t kb = (size_t)(8 + kc * 4 + lg) * 512;
#pragma unroll
        for (int nt = 0; nt < 4; ++nt) {
            int c = w * 64 + nt * 16 + lr;
            bf16x8 b = __builtin_bit_cast(bf16x8, *(const u16x8*)(nw1p + (kb + c) * 8));
            acc[nt] = __builtin_amdgcn_mfma_f32_16x16x32_bf16(a, b, acc[nt], 0, 0, 0);
        }
    }
#pragma unroll
    for (int reg = 0; reg < 4; ++reg)
#pragma unroll
        for (int nt = 0; nt < 4; ++nt) {
            int k = rb + lg * 4 + reg;
            int c = w * 64 + nt * 16 + lr;
            Wfp[((size_t)(k >> 3) * 512 + c) * 8 + (k & 7)] = f2bf(acc[nt][reg]);
        }
}

// ---------------------------------------------------------------------------
// pq_xa: y<2 -> PQ halves (+eb1 on P); y==2 -> R(bf16) = [X|onehot]@nw1[0:64]+nbf.
__global__ __launch_bounds__(256) void pq_xa(
    const float* __restrict__ X, const int* __restrict__ act,
    const unsigned short* __restrict__ ew1p, const unsigned short* __restrict__ nw1p,
    const float* __restrict__ eb1, const float* __restrict__ nbf,
    unsigned short* __restrict__ PQ, unsigned short* __restrict__ Rb)
{
    const int t = threadIdx.x, w = t >> 6, lane = t & 63;
    const int lr = lane & 15, lg = lane >> 4;
    const int rb = blockIdx.x * 32;
    const int mode = blockIdx.y;

    bf16x8 a[2];
#pragma unroll
    for (int m = 0; m < 2; ++m) {
        const float* s = X + (size_t)(rb + m * 16 + lr) * 32 + lg * 8;
        float4 x0 = *(const float4*)s, x1 = *(const float4*)(s + 4);
        u16x8 u;
        u[0] = f2bf(x0.x); u[1] = f2bf(x0.y); u[2] = f2bf(x0.z); u[3] = f2bf(x0.w);
        u[4] = f2bf(x1.x); u[5] = f2bf(x1.y); u[6] = f2bf(x1.z); u[7] = f2bf(x1.w);
        a[m] = __builtin_bit_cast(bf16x8, u);
    }

    if (mode < 2) {
        const int half = mode;
        f32x4 acc[2][8] = {};
#pragma unroll
        for (int nt = 0; nt < 8; ++nt) {
            int col = half * 512 + w * 128 + nt * 16 + lr;
            bf16x8 b = __builtin_bit_cast(bf16x8, *(const u16x8*)(ew1p + ((size_t)lg * 1024 + col) * 8));
            acc[0][nt] = __builtin_amdgcn_mfma_f32_16x16x32_bf16(a[0], b, acc[0][nt], 0, 0, 0);
            acc[1][nt] = __builtin_amdgcn_mfma_f32_16x16x32_bf16(a[1], b, acc[1][nt], 0, 0, 0);
        }
#pragma unroll
        for (int nt = 0; nt < 8; ++nt) {
            int col = w * 128 + nt * 16 + lr;
            float eb = (half == 0) ? eb1[col] : 0.f;
#pragma unroll
            for (int m = 0; m < 2; ++m)
#pragma unroll
                for (int reg = 0; reg < 4; ++reg)
                    PQ[(size_t)(rb + m * 16 + lg * 4 + reg) * 1024 + half * 512 + col]
                        = f2bf(acc[m][nt][reg] + eb);
        }
    } else {
        bf16x8 a1[2];
#pragma unroll
        for (int m = 0; m < 2; ++m) {
            int row = rb + m * 16 + lr;
            u16x8 v = (u16x8)(unsigned short)0;
            if (lg == 0) {
                int ac = act[row / KOBJ];
                v[ac & 3] = (unsigned short)0x3f80;    // bf16(1.0) at k=32+ac
            }
            a1[m] = __builtin_bit_cast(bf16x8, v);
        }
        f32x4 acc[2][8] = {};
#pragma unroll
        for (int nt = 0; nt < 8; ++nt) {
            int col = w * 128 + nt * 16 + lr;
            bf16x8 b0 = __builtin_bit_cast(bf16x8, *(const u16x8*)(nw1p + ((size_t)lg * 512 + col) * 8));
            bf16x8 b1 = __builtin_bit_cast(bf16x8, *(const u16x8*)(nw1p + ((size_t)(4 + lg) * 512 + col) * 8));
#pragma unroll
            for (int m = 0; m < 2; ++m) {
                acc[m][nt] = __builtin_amdgcn_mfma_f32_16x16x32_bf16(a[m], b0, acc[m][nt], 0, 0, 0);
                acc[m][nt] = __builtin_amdgcn_mfma_f32_16x16x32_bf16(a1[m], b1, acc[m][nt], 0, 0, 0);
            }
        }
#pragma unroll
        for (int nt = 0; nt < 8; ++nt) {
            int col = w * 128 + nt * 16 + lr;
            float bb = nbf[col];
#pragma unroll
            for (int m = 0; m < 2; ++m)
#pragma unroll
                for (int reg = 0; reg < 4; ++reg)
                    Rb[(size_t)(rb + m * 16 + lg * 4 + reg) * 512 + col]
                        = f2bf(acc[m][nt][reg] + bb);
        }
    }
}

// ---------------------------------------------------------------------------
// edge_v15 (unchanged, proven 96.3 us).
__global__ __launch_bounds__(512, 4) void edge_v15(
    const unsigned short* __restrict__ PQ, const unsigned short* __restrict__ ew2p,
    const float* __restrict__ eb2, const float* __restrict__ eg,
    const float* __restrict__ ebt, unsigned short* __restrict__ Spart)
{
    __shared__ __align__(16) char ldsraw[77824];   // B dbuf | A dbuf; epilogue: Hcol
    __shared__ float sums[64], ssums[64];
    unsigned short* Hcol = (unsigned short*)ldsraw;          // stride 72 u16/col

    const int t = threadIdx.x, w = t >> 6, lane = t & 63;
    const int lr = lane & 15, lg = lane >> 4;
    const int wr = w >> 2, wc = w & 3;
    const int rb = blockIdx.x * 64;

    if (t < 64) { sums[t] = 0.f; ssums[t] = 0.f; }

    const bool ab = (t < 256);
    const int arow = t >> 2, akg = t & 3;
    const int e = rb + arow;
    const int g = e / 90, le = e - g * 90;
    const int i = le / 9, jj = le - i * 9;
    const int j = jj + (jj >= i);
    const unsigned short* pqP = PQ + ((size_t)(g * KOBJ + i)) * 1024 + akg * 8;
    const unsigned short* pqQ = PQ + ((size_t)(g * KOBJ + j)) * 1024 + 512 + akg * 8;

    u16x8 rp = (u16x8)(unsigned short)0, rq = (u16x8)(unsigned short)0;
    auto loadPQ = [&](int kc) {
        if (ab) {
            rp = *(const u16x8*)(pqP + kc * 32);
            rq = *(const u16x8*)(pqQ + kc * 32);
        }
    };
    auto buildA = [&](int buf) {
        if (ab) {
            u16x8 o;
#pragma unroll
            for (int q = 0; q < 8; ++q)
                o[q] = f2bf(fmaxf(bf2f(rp[q]) + bf2f(rq[q]), 0.f));
            *(u16x8*)(ldsraw + 65536 + buf * 5120 + arow * 80 + akg * 16) = o;
        }
    };
    auto fillB = [&](int kc, int buf) {
        char* Bb = ldsraw + buf * 32768;
#pragma unroll
        for (int RR = 0; RR < 4; ++RR)
            gl_lds16(ew2p + (size_t)kc * 16384 + RR * 4096 + t * 8, Bb + RR * 8192 + w * 1024);
    };

    f32x4 acc[2][8] = {};
    loadPQ(0); buildA(0); loadPQ(1); fillB(0, 0);
    __syncthreads();
    int cur = 0;
    for (int kc = 0; kc < 16; ++kc) {
        if (kc < 15) {
            fillB(kc + 1, cur ^ 1);
            buildA(cur ^ 1);                   // consumes regs prefetched for kc+1
            if (kc < 14) loadPQ(kc + 2);
        }
        const unsigned short* Ab = (const unsigned short*)(ldsraw + 65536 + cur * 5120);
        const unsigned short* Bb = (const unsigned short*)(ldsraw + cur * 32768);
        bf16x8 a0 = *(const bf16x8*)(Ab + (wr * 32 + lr) * 40 + lg * 8);
        bf16x8 a1 = *(const bf16x8*)(Ab + (wr * 32 + 16 + lr) * 40 + lg * 8);
#pragma unroll
        for (int nt = 0; nt < 8; ++nt) {
            bf16x8 b = *(const bf16x8*)(Bb + ((size_t)lg * 512 + wc * 128 + nt * 16 + lr) * 8);
            acc[0][nt] = __builtin_amdgcn_mfma_f32_16x16x32_bf16(a0, b, acc[0][nt], 0, 0, 0);
            acc[1][nt] = __builtin_amdgcn_mfma_f32_16x16x32_bf16(a1, b, acc[1][nt], 0, 0, 0);
        }
        __syncthreads();
        cur ^= 1;
    }

    float b2[8], gv[8], bb[8];
#pragma unroll
    for (int nt = 0; nt < 8; ++nt) {
        int c = wc * 128 + nt * 16 + lr;
        b2[nt] = eb2[c]; gv[nt] = eg[c]; bb[nt] = ebt[c];
    }
#pragma unroll
    for (int m = 0; m < 2; ++m)
#pragma unroll
        for (int reg = 0; reg < 4; ++reg) {
            float s = 0.f, ss = 0.f;
#pragma unroll
            for (int nt = 0; nt < 8; ++nt) {
                float v = acc[m][nt][reg] + b2[nt];
                acc[m][nt][reg] = v;
                s += v; ss += v * v;
            }
#pragma unroll
            for (int msk = 1; msk < 16; msk <<= 1) {
                s  += __shfl_xor(s,  msk, 64);
                ss += __shfl_xor(ss, msk, 64);
            }
            if (lr == 0) {
                int rl = wr * 32 + m * 16 + lg * 4 + reg;
                atomicAdd(&sums[rl], s);
                atomicAdd(&ssums[rl], ss);
            }
        }
    __syncthreads();

#pragma unroll
    for (int m = 0; m < 2; ++m)
#pragma unroll
        for (int nt = 0; nt < 8; ++nt) {
            int c = wc * 128 + nt * 16 + lr;
            u16x4 o;
#pragma unroll
            for (int reg = 0; reg < 4; ++reg) {
                int rl = wr * 32 + m * 16 + lg * 4 + reg;
                float mean = sums[rl] * (1.f / 512.f);
                float var  = ssums[rl] * (1.f / 512.f) - mean * mean;
                float inv  = rsqrtf(var + LN_EPS);
                float h = fmaxf((acc[m][nt][reg] - mean) * inv * gv[nt] + bb[nt], 0.f);
                o[reg] = f2bf(h);
            }
            *(u16x4*)(&Hcol[c * 72 + wr * 32 + m * 16 + lg * 4]) = o;
        }
    __syncthreads();

    // MFMA aggregation: Spart[node][col] = I[node][row] @ H[row][col]  (bf16 out)
    {
        const int n0 = rb / 9;
        f32x4 sacc[4] = {};
#pragma unroll
        for (int kc2 = 0; kc2 < 2; ++kc2) {
            u16x8 ia;
#pragma unroll
            for (int q = 0; q < 8; ++q) {
                int k = kc2 * 32 + lg * 8 + q;
                int node = (rb + k) / 9 - n0;            // 0..7
                ia[q] = (node == lr) ? (unsigned short)0x3F80 : (unsigned short)0;
            }
            bf16x8 af = __builtin_bit_cast(bf16x8, ia);
#pragma unroll
            for (int nt = 0; nt < 4; ++nt) {
                int c = w * 64 + nt * 16 + lr;
                bf16x8 bf = *(const bf16x8*)(&Hcol[c * 72 + kc2 * 32 + lg * 8]);
                sacc[nt] = __builtin_amdgcn_mfma_f32_16x16x32_bf16(af, bf, sacc[nt], 0, 0, 0);
            }
        }
        if (lg < 2) {
            unsigned short* dst = Spart + (size_t)blockIdx.x * 4096;
#pragma unroll
            for (int nt = 0; nt < 4; ++nt)
#pragma unroll
                for (int reg = 0; reg < 4; ++reg) {
                    int node = lg * 4 + reg;
                    int c = w * 64 + nt * 16 + lr;
                    dst[node * 512 + c] = f2bf(sacc[nt][reg]);
                }
        }
    }
}

// ---------------------------------------------------------------------------
// node_hh13: Hh = relu(gather(Spart)@Wfp + R). Grid (160,2). (proven v17)
__global__ __launch_bounds__(512, 4) void node_hh13(
    const unsigned short* __restrict__ Spart, const unsigned short* __restrict__ Wfp,
    const unsigned short* __restrict__ Rb, unsigned short* __restrict__ Hh)
{
    __shared__ __align__(16) unsigned short Bsh[2][8192];   // 2 x 16KB [kbl][256][8]
    __shared__ __align__(16) unsigned short Ash[2][2560];   // 2 x 5KB  [row*40 + k]
    const int t = threadIdx.x, w = t >> 6, lane = t & 63;
    const int lr = lane & 15, lg = lane >> 4;
    const int wr = w >> 2, wc = w & 3;
    const int rb = blockIdx.x * 64;
    const int nh = blockIdx.y;                              // col base nh*256

    const bool ab = (t < 256);
    const int arow = t >> 2, akg = t & 3;
    const int n = rb + arow;
    const int e0 = 9 * n;
    const int b1 = e0 >> 6, b2 = (e0 + 8) >> 6;
    const int nl1 = n - (b1 * 64) / 9;
    const int nl2 = n - (b2 * 64) / 9;
    const unsigned short* p1 = Spart + ((size_t)b1 * 8 + nl1) * 512 + akg * 8;
    const unsigned short* p2 = Spart + ((size_t)b2 * 8 + nl2) * 512 + akg * 8;
    const bool two = (b2 != b1);

    u16x8 r1 = (u16x8)(unsigned short)0, r2 = (u16x8)(unsigned short)0;
    auto loadA = [&](int kc) {
        if (ab) {
            r1 = *(const u16x8*)(p1 + kc * 32);
            if (two) r2 = *(const u16x8*)(p2 + kc * 32);
        }
    };
    auto buildA = [&](int buf) {
        if (ab) {
            u16x8 o;
#pragma unroll
            for (int q = 0; q < 8; ++q) {
                float s = bf2f(r1[q]) + (two ? bf2f(r2[q]) : 0.f);
                o[q] = f2bf(s);
            }
            *(u16x8*)(&Ash[buf][arow * 40 + akg * 8]) = o;
        }
    };
    auto fillB = [&](int kc, int buf) {
        char* Bb = (char*)&Bsh[buf][0];
#pragma unroll
        for (int RR = 0; RR < 2; ++RR) {
            int gi = RR * 512 + t;
            int kbl = gi >> 8, col = gi & 255;
            gl_lds16(Wfp + ((size_t)(kc * 4 + kbl) * 512 + nh * 256 + col) * 8,
                     Bb + RR * 8192 + w * 1024);
        }
    };

    f32x4 acc[2][4] = {};
    loadA(0); buildA(0); loadA(1); fillB(0, 0);
    __syncthreads();
    int cur = 0;
    for (int kc = 0; kc < 16; ++kc) {
        if (kc < 15) {
            fillB(kc + 1, cur ^ 1);
            buildA(cur ^ 1);
            if (kc < 14) loadA(kc + 2);
        }
        const unsigned short* Ab = &Ash[cur][0];
        const unsigned short* Bb = &Bsh[cur][0];
        bf16x8 a0 = *(const bf16x8*)(Ab + (wr * 32 + lr) * 40 + lg * 8);
        bf16x8 a1 = *(const bf16x8*)(Ab + (wr * 32 + 16 + lr) * 40 + lg * 8);
#pragma unroll
        for (int nt = 0; nt < 4; ++nt) {
            bf16x8 b = *(const bf16x8*)(Bb + ((size_t)lg * 256 + wc * 64 + nt * 16 + lr) * 8);
            acc[0][nt] = __builtin_amdgcn_mfma_f32_16x16x32_bf16(a0, b, acc[0][nt], 0, 0, 0);
            acc[1][nt] = __builtin_amdgcn_mfma_f32_16x16x32_bf16(a1, b, acc[1][nt], 0, 0, 0);
        }
        __syncthreads();
        cur ^= 1;
    }

#pragma unroll
    for (int m = 0; m < 2; ++m)
#pragma unroll
        for (int reg = 0; reg < 4; ++reg) {
            int row = rb + wr * 32 + m * 16 + lg * 4 + reg;
#pragma unroll
            for (int nt = 0; nt < 4; ++nt) {
                int c = nh * 256 + wc * 64 + nt * 16 + lr;
                float v = acc[m][nt][reg] + bf2f(Rb[(size_t)row * 512 + c]);
                Hh[(size_t)row * 512 + c] = f2bf(fmaxf(v, 0.f));
            }
        }
}

// ---------------------------------------------------------------------------
// node_lo: H2 = relu(LN(Hh@nw2 + nb2)*ng+nbt) kept in LDS; out = H2@nw3 + nb3.
__global__ __launch_bounds__(512, 4) void node_lo(
    const unsigned short* __restrict__ A, const unsigned short* __restrict__ Wp,
    const float* __restrict__ bias, const float* __restrict__ gamma,
    const float* __restrict__ beta, const unsigned short* __restrict__ nw3p,
    const float* __restrict__ nb3, float* __restrict__ out)
{
    __shared__ __align__(16) char raw[69632];      // 64KB Bt | 4KB At
    __shared__ float sums[32], ssums[32];
    unsigned short* Bt = (unsigned short*)raw;
    unsigned short* At = (unsigned short*)(raw + 65536);
    const int t = threadIdx.x, w = t >> 6, lane = t & 63;
    const int lr = lane & 15, lg = lane >> 4;
    const int rb = blockIdx.x * 32;
    if (t < 32) { sums[t] = 0.f; ssums[t] = 0.f; }

    f32x4 acc[2][4] = {};
    for (int kc = 0; kc < 8; ++kc) {
        __syncthreads();
#pragma unroll
        for (int RR = 0; RR < 8; ++RR)
            gl_lds16(Wp + ((size_t)kc * 4096 + RR * 512 + t) * 8,
                     raw + RR * 8192 + w * 1024);
        if (w < 4) {
            int row = t >> 3, cp = t & 7;
            int scol = cp ^ (row & 7);
            gl_lds16(A + (size_t)(rb + row) * 512 + kc * 64 + scol * 8,
                     raw + 65536 + (t & ~63) * 16);
        }
        __syncthreads();
#pragma unroll
        for (int ks = 0; ks < 2; ++ks) {
            int kidx = ks * 4 + lg;
            bf16x8 a0 = *(const bf16x8*)(At + ( 0 + lr) * 64 + (kidx ^ (lr & 7)) * 8);
            bf16x8 a1 = *(const bf16x8*)(At + (16 + lr) * 64 + (kidx ^ (lr & 7)) * 8);
#pragma unroll
            for (int nt = 0; nt < 4; ++nt) {
                bf16x8 b = *(const bf16x8*)(Bt + ((size_t)kidx * 512 + w * 64 + nt * 16 + lr) * 8);
                acc[0][nt] = __builtin_amdgcn_mfma_f32_16x16x32_bf16(a0, b, acc[0][nt], 0, 0, 0);
                acc[1][nt] = __builtin_amdgcn_mfma_f32_16x16x32_bf16(a1, b, acc[1][nt], 0, 0, 0);
            }
        }
    }

    float bv[4], gv[4], be[4];
#pragma unroll
    for (int nt = 0; nt < 4; ++nt) {
        int c = w * 64 + nt * 16 + lr;
        bv[nt] = bias[c]; gv[nt] = gamma[c]; be[nt] = beta[c];
    }
#pragma unroll
    for (int m = 0; m < 2; ++m)
#pragma unroll
        for (int reg = 0; reg < 4; ++reg) {
            float s = 0.f, ss = 0.f;
#pragma unroll
            for (int nt = 0; nt < 4; ++nt) {
                float v = acc[m][nt][reg] + bv[nt];
                acc[m][nt][reg] = v;
                s += v; ss += v * v;
            }
#pragma unroll
            for (int msk = 1; msk < 16; msk <<= 1) {
                s  += __shfl_xor(s,  msk, 64);
                ss += __shfl_xor(ss, msk, 64);
            }
            if (lr == 0) {
                atomicAdd(&sums [m * 16 + lg * 4 + reg], s);
                atomicAdd(&ssums[m * 16 + lg * 4 + reg], ss);
            }
        }
    __syncthreads();   // stats done; loop LDS reads done -> raw reusable

    // normalize + relu -> Hst[32][520] u16 (LDS only)
    unsigned short* Hst = (unsigned short*)raw;
#pragma unroll
    for (int m = 0; m < 2; ++m)
#pragma unroll
        for (int reg = 0; reg < 4; ++reg) {
            int rl = m * 16 + lg * 4 + reg;
            float mean = sums[rl] * (1.f / 512.f);
            float var  = ssums[rl] * (1.f / 512.f) - mean * mean;
            float inv  = rsqrtf(var + LN_EPS);
#pragma unroll
            for (int nt = 0; nt < 4; ++nt) {
                int c = w * 64 + nt * 16 + lr;
                float v = fmaxf((acc[m][nt][reg] - mean) * inv * gv[nt] + be[nt], 0.f);
                Hst[rl * 520 + c] = f2bf(v);
            }
        }
    __syncthreads();

    // out-GEMM: wave w handles k in [w*64, w*64+64).
    float* Pp = (float*)(raw + 34816);           // [8][32][32] f32
    {
        f32x4 acc2[2][2] = {};
#pragma unroll
        for (int kc3 = 0; kc3 < 2; ++kc3) {
            int kbase = w * 64 + kc3 * 32;
            bf16x8 a0 = *(const bf16x8*)(Hst + ( 0 + lr) * 520 + kbase + lg * 8);
            bf16x8 a1 = *(const bf16x8*)(Hst + (16 + lr) * 520 + kbase + lg * 8);
#pragma unroll
            for (int ntt = 0; ntt < 2; ++ntt) {
                int kb = (kbase >> 3) + lg;
                bf16x8 b = __builtin_bit_cast(bf16x8,
                    *(const u16x8*)(nw3p + ((size_t)kb * 32 + ntt * 16 + lr) * 8));
                acc2[0][ntt] = __builtin_amdgcn_mfma_f32_16x16x32_bf16(a0, b, acc2[0][ntt], 0, 0, 0);
                acc2[1][ntt] = __builtin_amdgcn_mfma_f32_16x16x32_bf16(a1, b, acc2[1][ntt], 0, 0, 0);
            }
        }
        __syncthreads();
#pragma unroll
        for (int mt = 0; mt < 2; ++mt)
#pragma unroll
            for (int ntt = 0; ntt < 2; ++ntt)
#pragma unroll
                for (int reg = 0; reg < 4; ++reg) {
                    int row = mt * 16 + lg * 4 + reg;
                    int col = ntt * 16 + lr;
                    Pp[(size_t)w * 1024 + row * 32 + col] = acc2[mt][ntt][reg];
                }
    }
    __syncthreads();

    for (int e2 = t; e2 < 1024; e2 += 512) {
        int row = e2 >> 5, col = e2 & 31;
        float s = 0.f;
#pragma unroll
        for (int ww = 0; ww < 8; ++ww) s += Pp[(size_t)ww * 1024 + e2];
        out[(size_t)(rb + row) * 32 + col] = s + nb3[col];
    }
}

// ---------------------------------------------------------------------------
extern "C" void kernel_launch(void* const* d_in, const int* in_sizes, int n_in,
                              void* d_out, int out_size, void* d_ws, size_t ws_size,
                              hipStream_t stream)
{
    const float* states = (const float*)d_in[0];
    const int*   action = (const int*)d_in[1];
    const float* ew1 = (const float*)d_in[2];
    const float* eb1 = (const float*)d_in[3];
    const float* ew2 = (const float*)d_in[4];
    const float* eb2 = (const float*)d_in[5];
    const float* eg  = (const float*)d_in[6];
    const float* ebt = (const float*)d_in[7];
    const float* ew3 = (const float*)d_in[8];
    const float* eb3 = (const float*)d_in[9];
    const float* nw1 = (const float*)d_in[10];
    const float* nb1 = (const float*)d_in[11];
    const float* nw2 = (const float*)d_in[12];
    const float* nb2 = (const float*)d_in[13];
    const float* ng  = (const float*)d_in[14];
    const float* nbt = (const float*)d_in[15];
    const float* nw3 = (const float*)d_in[16];
    const float* nb3 = (const float*)d_in[17];

    char* wsb = (char*)d_ws;
    unsigned short* PQ    = (unsigned short*)(wsb);               // 10240x1024 bf16
    unsigned short* Spart = (unsigned short*)(wsb + 20971520);    // 1440x8x512 bf16
    unsigned short* Rb    = (unsigned short*)(wsb + 43253760);    // 10240x512 bf16
    unsigned short* Hh    = (unsigned short*)(wsb + 53739520);    // 10240x512 bf16
    unsigned short* ew1p  = (unsigned short*)(wsb + 74711040);    // 32x1024
    unsigned short* ew2p  = (unsigned short*)(wsb + 74776576);    // 512x512 packed
    unsigned short* nw1p  = (unsigned short*)(wsb + 75300864);    // 576x512 packed
    unsigned short* nw2p  = (unsigned short*)(wsb + 75890688);    // 512x512 packed
    unsigned short* Wfp   = (unsigned short*)(wsb + 76414976);    // 512x512 packed
    float*          nbf   = (float*)         (wsb + 76939264);    // 512 f32
    unsigned short* nw3p  = (unsigned short*)(wsb + 76941312);    // 512x32 packed
    float* out = (float*)d_out;

    hipLaunchKernelGGL(megapack, dim3(3392), dim3(256), 0, stream,
                       ew1, ew2, nw1, nw2, nw3, ew1p, ew2p, nw1p, nw2p, nw3p);
    hipLaunchKernelGGL(fold_w2, dim3(33), dim3(512), 0, stream,
                       ew3, nw1p, nw1, nb1, eb3, Wfp, nbf);
    hipLaunchKernelGGL(pq_xa, dim3(320, 3), dim3(256), 0, stream,
                       states, action, ew1p, nw1p, eb1, nbf, PQ, Rb);
    hipLaunchKernelGGL(edge_v15, dim3(NBLK), dim3(512), 0, stream,
                       PQ, ew2p, eb2, eg, ebt, Spart);
    hipLaunchKernelGGL(node_hh13, dim3(160, 2), dim3(512), 0, stream,
                       Spart, Wfp, Rb, Hh);
    hipLaunchKernelGGL(node_lo, dim3(320), dim3(512), 0, stream,
                       Hh, nw2p, nb2, ng, nbt, nw3p, nb3, out);
}